// Round 10
// baseline (2430.855 us; speedup 1.0000x reference)
//
#include <hip/hip_runtime.h>

#define P 16384
#define NLAYERS 5
#define NND 98304          // P*(NLAYERS+1)
#define D 64
#define S 16
#define F 80               // D+S
#define KP1 96             // K of layer-1 GEMM padded to 32
#define H 256
#define EDG 262144         // 1<<18
#define NG 64
#define NSETS 13           // 5 inner + 4 fwd + 4 bwd
#define RSP 16385          // rowstart pitch (P+1)
#define LDP 40             // LDS K-stride for 32-chunks (80B rows, <=2-way aliasing)
#define LDA1 104           // LDS row stride for conv1 A (96+8 pad, 208B, bank-stride 20)

typedef __attribute__((ext_vector_type(8))) short s16x8;
typedef __attribute__((ext_vector_type(4))) float f32x4;

// ---------------------------------------------------------------- utilities
__device__ __forceinline__ void fatomic_add(float* p, float v) {
    unsafeAtomicAdd(p, v);
}
__device__ __forceinline__ unsigned short bf16_rne(float x) {
    unsigned int u = __float_as_uint(x);
    unsigned int r = u + 0x7fffu + ((u >> 16) & 1u);
    return (unsigned short)(r >> 16);
}
__device__ __forceinline__ float bf16_to_f(unsigned short b) {
    return __uint_as_float(((unsigned int)b) << 16);
}

// ---------------------------------------------------------------- init X + zero deg + zero PL
__global__ void k_init_x(const float* __restrict__ x0, float* __restrict__ X,
                         int* __restrict__ deg, float* __restrict__ PL) {
    int idx = blockIdx.x * blockDim.x + threadIdx.x;
    if (idx < NND * D) {
        int row = idx >> 6, f = idx & 63;
        X[idx] = (f == 0) ? x0[row] : 0.0f;
        return;
    }
    int r = idx - NND * D;
    if (r < NSETS * P) { deg[r] = 0; return; }
    r -= NSETS * P;
    if (r < NG * D) PL[r] = 0.0f;
}

// ---------------------------------------------------------------- weight transpose + split (all 3 layers)
__global__ void k_wsplit_all(const float* __restrict__ W1, const float* __restrict__ W2,
                             const float* __restrict__ W3,
                             unsigned short* __restrict__ w1h, unsigned short* __restrict__ w1l,
                             unsigned short* __restrict__ w2h, unsigned short* __restrict__ w2l,
                             unsigned short* __restrict__ w3h, unsigned short* __restrict__ w3l) {
    const int n1 = 4 * H * KP1, n2 = 4 * H * H, n3 = 4 * D * H;
    int idx = blockIdx.x * blockDim.x + threadIdx.x;
    const float* W; unsigned short *h, *l; int K, N, Kp, i;
    if (idx < n1)              { W = W1; h = w1h; l = w1l; K = F; N = H; Kp = KP1; i = idx; }
    else if (idx < n1 + n2)    { W = W2; h = w2h; l = w2l; K = H; N = H; Kp = H;   i = idx - n1; }
    else if (idx < n1 + n2 + n3){ W = W3; h = w3h; l = w3l; K = H; N = D; Kp = H;  i = idx - n1 - n2; }
    else return;
    int set = i / (N * Kp), rem = i - set * (N * Kp);
    int n = rem / Kp, kp = rem - n * Kp;
    float v = (kp < K) ? W[(size_t)set * K * N + (size_t)kp * N + n] : 0.0f;
    unsigned short hh = bf16_rne(v);
    h[i] = hh;
    l[i] = bf16_rne(v - bf16_to_f(hh));
}

// ---------------------------------------------------------------- CSR build (batched, 13 sets)
__device__ __forceinline__ const int* set_ptr(int t, const int* inner, const int* fwd,
                                              const int* bwd) {
    if (t < 5) return inner + (size_t)t * EDG;
    if (t < 9) return fwd + (size_t)(t - 5) * EDG;
    return bwd + (size_t)(t - 9) * EDG;
}

__global__ void k_csr_hist(const int* __restrict__ inner_dst, const int* __restrict__ fwd_dst,
                           const int* __restrict__ bwd_dst, int* __restrict__ deg,
                           int* __restrict__ rank) {
    int idx = blockIdx.x * blockDim.x + threadIdx.x;
    if (idx >= NSETS * EDG) return;
    int t = idx >> 18, e = idx & (EDG - 1);
    const int* dstp = set_ptr(t, inner_dst, fwd_dst, bwd_dst);
    rank[idx] = atomicAdd(&deg[t * P + dstp[e]], 1);
}

__global__ __launch_bounds__(1024) void k_csr_scan(const int* __restrict__ deg,
                                                   int* __restrict__ rowstart) {
    __shared__ int part[1024];
    int t = blockIdx.x;
    const int* d = deg + t * P;
    int* rs = rowstart + (size_t)t * RSP;
    int tid = threadIdx.x;
    int base = tid * 16;
    int loc[16], sum = 0;
#pragma unroll
    for (int i = 0; i < 16; ++i) { loc[i] = sum; sum += d[base + i]; }
    part[tid] = sum;
    __syncthreads();
    for (int off = 1; off < 1024; off <<= 1) {
        int v = (tid >= off) ? part[tid - off] : 0;
        __syncthreads();
        part[tid] += v;
        __syncthreads();
    }
    int pre = tid ? part[tid - 1] : 0;
#pragma unroll
    for (int i = 0; i < 16; ++i) rs[base + i] = pre + loc[i];
    if (tid == 1023) rs[P] = pre + sum;
}

__global__ void k_csr_scatter(const int* __restrict__ inner_src, const int* __restrict__ inner_dst,
                              const int* __restrict__ fwd_src, const int* __restrict__ fwd_dst,
                              const int* __restrict__ bwd_src, const int* __restrict__ bwd_dst,
                              const int* __restrict__ rowstart, const int* __restrict__ rank,
                              int* __restrict__ elist) {
    int idx = blockIdx.x * blockDim.x + threadIdx.x;
    if (idx >= NSETS * EDG) return;
    int t = idx >> 18, e = idx & (EDG - 1);
    const int* srcp = set_ptr(t, inner_src, fwd_src, bwd_src);
    const int* dstp = set_ptr(t, inner_dst, fwd_dst, bwd_dst);
    int dv = dstp[e];
    elist[(size_t)t * EDG + rowstart[(size_t)t * RSP + dv] + rank[idx]] = srcp[e];
}

// ---------------------------------------------------------------- fused gather + GEMM1 (64x256 tile, 8 waves)
// Block owns 64 dst rows. Phase A: aggregate (or copy) rows into LDS split planes.
// Phase B: H1[rows] = relu(A @ W1t^T + b1), B-fragments read directly from global (L2-resident).
__global__ __launch_bounds__(512) void k_conv1(
    const float* __restrict__ X, const float* __restrict__ st,
    const int* __restrict__ elist, const int* __restrict__ rowstart,
    int dst_gbase, int src_gbase,
    const float* __restrict__ eps, int ei,
    const unsigned short* __restrict__ Wh, const unsigned short* __restrict__ Wl,  // [256][96]
    const float* __restrict__ bias,
    unsigned short* __restrict__ Ch, unsigned short* __restrict__ Cl)              // [P][256]
{
    __shared__ unsigned short Ath[64][LDA1], Atl[64][LDA1];   // 26.6 KB

    int tid = threadIdx.x;
    int lane = tid & 63, wid = tid >> 6;
    int r0 = blockIdx.x * 64;
    float scale = (ei >= 0) ? 1.0f + eps[ei] : 1.0f;

    // ---- phase A: wave-per-row aggregation (8 rows per wave)
    for (int rr = wid; rr < 64; rr += 8) {
        int v = r0 + rr;
        int g = dst_gbase + v;
        float accX = X[(size_t)g * D + lane] * scale;
        float accS = (lane < S) ? st[(size_t)g * S + lane] * scale : 0.0f;
        if (rowstart) {
            int beg = rowstart[v], end = rowstart[v + 1];
            for (int i = beg; i < end; ++i) {
                int s = src_gbase + elist[i];        // wave-uniform
                accX += X[(size_t)s * D + lane];
                if (lane < S) accS += st[(size_t)s * S + lane];
            }
        }
        unsigned short hx = bf16_rne(accX);
        Ath[rr][lane] = hx;
        Atl[rr][lane] = bf16_rne(accX - bf16_to_f(hx));
        if (lane < 32) {
            float vs = (lane < S) ? accS : 0.0f;     // cols 80..95 zero pad
            unsigned short hs = bf16_rne(vs);
            Ath[rr][D + lane] = hs;
            Atl[rr][D + lane] = (lane < S) ? bf16_rne(vs - bf16_to_f(hs)) : (unsigned short)0;
        }
    }
    __syncthreads();

    // ---- phase B: 8 waves as 2(m) x 4(n); wave tile 32x64
    int wm = wid >> 2, wn = wid & 3;
    int la = lane & 15, lg = lane >> 4;
    f32x4 acc[2][4] = {};

#pragma unroll
    for (int k0 = 0; k0 < KP1; k0 += 32) {
        int kf = k0 + lg * 8;
        s16x8 ah[2], al[2], bh[4], bl[4];
#pragma unroll
        for (int m = 0; m < 2; ++m) {
            int r = wm * 32 + m * 16 + la;
            ah[m] = *(const s16x8*)&Ath[r][kf];
            al[m] = *(const s16x8*)&Atl[r][kf];
        }
#pragma unroll
        for (int n = 0; n < 4; ++n) {
            int col = wn * 64 + n * 16 + la;
            size_t ob = (size_t)col * KP1 + kf;
            bh[n] = *(const s16x8*)&Wh[ob];
            bl[n] = *(const s16x8*)&Wl[ob];
        }
#pragma unroll
        for (int m = 0; m < 2; ++m)
#pragma unroll
            for (int n = 0; n < 4; ++n) {
                acc[m][n] = __builtin_amdgcn_mfma_f32_16x16x32_bf16(ah[m], bh[n], acc[m][n], 0, 0, 0);
                acc[m][n] = __builtin_amdgcn_mfma_f32_16x16x32_bf16(ah[m], bl[n], acc[m][n], 0, 0, 0);
                acc[m][n] = __builtin_amdgcn_mfma_f32_16x16x32_bf16(al[m], bh[n], acc[m][n], 0, 0, 0);
            }
    }

#pragma unroll
    for (int n = 0; n < 4; ++n) {
        int col = wn * 64 + n * 16 + la;
        float bv = bias[col];
#pragma unroll
        for (int m = 0; m < 2; ++m) {
            int row = r0 + wm * 32 + m * 16 + lg * 4;
#pragma unroll
            for (int r = 0; r < 4; ++r) {
                float v = fmaxf(acc[m][n][r] + bv, 0.0f);
                size_t o = (size_t)(row + r) * H + col;
                unsigned short hh = bf16_rne(v);
                Ch[o] = hh;
                Cl[o] = bf16_rne(v - bf16_to_f(hh));
            }
        }
    }
}

// ---------------------------------------------------------------- big split-bf16 MFMA GEMM (128x128, 8 waves) — GEMM2
__global__ __launch_bounds__(512) void k_gemm_big(
    const unsigned short* __restrict__ Ahp, const unsigned short* __restrict__ Alp, int lda,
    const unsigned short* __restrict__ Wh, const unsigned short* __restrict__ Wl, int Kp,
    const float* __restrict__ bias,
    unsigned short* __restrict__ Ch, unsigned short* __restrict__ Cl, int ldc)
{
    __shared__ unsigned short Ah[128][LDP], Al[128][LDP];
    __shared__ unsigned short Bh[128][LDP], Bl[128][LDP];   // 40 KB total

    int tid = threadIdx.x;
    int lane = tid & 63, wid = tid >> 6;       // 8 waves
    int wm = wid >> 2, wn = wid & 3;           // 2 x 4, wave tile 64x32
    int m0 = blockIdx.y * 128, n0 = blockIdx.x * 128;

    f32x4 acc[4][2] = {};

    int ar = tid >> 2;
    int ac = (tid & 3) * 8;
    int la = lane & 15, lg = lane >> 4;

    for (int k0 = 0; k0 < Kp; k0 += 32) {
        size_t oa = (size_t)(m0 + ar) * lda + k0 + ac;
        *(s16x8*)&Ah[ar][ac] = *(const s16x8*)&Ahp[oa];
        *(s16x8*)&Al[ar][ac] = *(const s16x8*)&Alp[oa];
        size_t ob = (size_t)(n0 + ar) * Kp + k0 + ac;
        *(s16x8*)&Bh[ar][ac] = *(const s16x8*)&Wh[ob];
        *(s16x8*)&Bl[ar][ac] = *(const s16x8*)&Wl[ob];
        __syncthreads();

        int kf = lg * 8;
        s16x8 ah[4], al[4], bh[2], bl[2];
#pragma unroll
        for (int m = 0; m < 4; ++m) {
            int r = wm * 64 + m * 16 + la;
            ah[m] = *(const s16x8*)&Ah[r][kf];
            al[m] = *(const s16x8*)&Al[r][kf];
        }
#pragma unroll
        for (int n = 0; n < 2; ++n) {
            int r = wn * 32 + n * 16 + la;
            bh[n] = *(const s16x8*)&Bh[r][kf];
            bl[n] = *(const s16x8*)&Bl[r][kf];
        }
#pragma unroll
        for (int m = 0; m < 4; ++m)
#pragma unroll
            for (int n = 0; n < 2; ++n) {
                acc[m][n] = __builtin_amdgcn_mfma_f32_16x16x32_bf16(ah[m], bh[n], acc[m][n], 0, 0, 0);
                acc[m][n] = __builtin_amdgcn_mfma_f32_16x16x32_bf16(ah[m], bl[n], acc[m][n], 0, 0, 0);
                acc[m][n] = __builtin_amdgcn_mfma_f32_16x16x32_bf16(al[m], bh[n], acc[m][n], 0, 0, 0);
            }
        __syncthreads();
    }

#pragma unroll
    for (int n = 0; n < 2; ++n) {
        int col = n0 + wn * 32 + n * 16 + la;
        float bv = bias[col];
#pragma unroll
        for (int m = 0; m < 4; ++m) {
            int row = m0 + wm * 64 + m * 16 + lg * 4;
#pragma unroll
            for (int r = 0; r < 4; ++r) {
                float v = fmaxf(acc[m][n][r] + bv, 0.0f);
                size_t o = (size_t)(row + r) * ldc + col;
                unsigned short hh = bf16_rne(v);
                Ch[o] = hh;
                Cl[o] = bf16_rne(v - bf16_to_f(hh));
            }
        }
    }
}

// ---------------------------------------------------------------- GEMM3 (64x64 tile, 4 waves) -> fp32 X
__global__ __launch_bounds__(256) void k_gemm_sm(
    const unsigned short* __restrict__ Ahp, const unsigned short* __restrict__ Alp, int lda,
    const unsigned short* __restrict__ Wh, const unsigned short* __restrict__ Wl, int Kp,
    const float* __restrict__ bias, float* __restrict__ Cf, int ldc)
{
    __shared__ unsigned short Ah[64][LDP], Al[64][LDP];
    __shared__ unsigned short Bh[64][LDP], Bl[64][LDP];    // 20.5 KB

    int tid = threadIdx.x;
    int lane = tid & 63, wid = tid >> 6;
    int wm = wid >> 1, wn = wid & 1;           // 2 x 2, wave tile 32x32
    int m0 = blockIdx.y * 64;

    f32x4 acc[2][2] = {};

    int sr = tid >> 2;
    int sc = (tid & 3) * 8;
    int la = lane & 15, lg = lane >> 4;

    for (int k0 = 0; k0 < Kp; k0 += 32) {
        size_t oa = (size_t)(m0 + sr) * lda + k0 + sc;
        *(s16x8*)&Ah[sr][sc] = *(const s16x8*)&Ahp[oa];
        *(s16x8*)&Al[sr][sc] = *(const s16x8*)&Alp[oa];
        size_t ob = (size_t)sr * Kp + k0 + sc;
        *(s16x8*)&Bh[sr][sc] = *(const s16x8*)&Wh[ob];
        *(s16x8*)&Bl[sr][sc] = *(const s16x8*)&Wl[ob];
        __syncthreads();

        int kf = lg * 8;
        s16x8 ah[2], al[2], bh[2], bl[2];
#pragma unroll
        for (int m = 0; m < 2; ++m) {
            int r = wm * 32 + m * 16 + la;
            ah[m] = *(const s16x8*)&Ah[r][kf];
            al[m] = *(const s16x8*)&Al[r][kf];
        }
#pragma unroll
        for (int n = 0; n < 2; ++n) {
            int r = wn * 32 + n * 16 + la;
            bh[n] = *(const s16x8*)&Bh[r][kf];
            bl[n] = *(const s16x8*)&Bl[r][kf];
        }
#pragma unroll
        for (int m = 0; m < 2; ++m)
#pragma unroll
            for (int n = 0; n < 2; ++n) {
                acc[m][n] = __builtin_amdgcn_mfma_f32_16x16x32_bf16(ah[m], bh[n], acc[m][n], 0, 0, 0);
                acc[m][n] = __builtin_amdgcn_mfma_f32_16x16x32_bf16(ah[m], bl[n], acc[m][n], 0, 0, 0);
                acc[m][n] = __builtin_amdgcn_mfma_f32_16x16x32_bf16(al[m], bh[n], acc[m][n], 0, 0, 0);
            }
        __syncthreads();
    }

#pragma unroll
    for (int n = 0; n < 2; ++n) {
        int col = wn * 32 + n * 16 + la;
        float bv = bias[col];
#pragma unroll
        for (int m = 0; m < 2; ++m) {
            int row = m0 + wm * 32 + m * 16 + lg * 4;
#pragma unroll
            for (int r = 0; r < 4; ++r) {
                Cf[(size_t)(row + r) * ldc + col] = fmaxf(acc[m][n][r] + bv, 0.0f);
            }
        }
    }
}

// ---------------------------------------------------------------- two-stage pooling
#define PROWS 1024
__global__ __launch_bounds__(256) void k_pool2(const float* __restrict__ X,
                                               const int* __restrict__ bidx,
                                               float* __restrict__ PL) {
    __shared__ float lds[NG * D];
    int tid = threadIdx.x;
    for (int i = tid; i < NG * D; i += 256) lds[i] = 0.0f;
    __syncthreads();
    int base = blockIdx.x * PROWS;
    int f = tid & 63, rg = tid >> 6;
    for (int r = base + rg; r < base + PROWS; r += 4) {
        int g = bidx[r];
        atomicAdd(&lds[g * D + f], X[(size_t)r * D + f]);
    }
    __syncthreads();
    for (int i = tid; i < NG * D; i += 256) {
        float v = lds[i];
        if (v != 0.0f) fatomic_add(&PL[i], v);
    }
}

// ---------------------------------------------------------------- final linear head
__global__ void k_final(const float* __restrict__ pooled, const float* __restrict__ lin_w,
                        const float* __restrict__ lin_b, float* __restrict__ out) {
    int g = threadIdx.x;
    if (g >= NG) return;
    float acc = lin_b[0];
#pragma unroll
    for (int d2 = 0; d2 < D; ++d2) acc += pooled[g * D + d2] * lin_w[d2];
    out[g] = fmaxf(acc, 0.0f);
}

// ---------------------------------------------------------------- launch
extern "C" void kernel_launch(void* const* d_in, const int* in_sizes, int n_in,
                              void* d_out, int out_size, void* d_ws, size_t ws_size,
                              hipStream_t stream) {
    const float* x0    = (const float*)d_in[0];
    const float* stat  = (const float*)d_in[1];
    const float* W1    = (const float*)d_in[2];
    const float* b1    = (const float*)d_in[3];
    const float* W2    = (const float*)d_in[4];
    const float* b2    = (const float*)d_in[5];
    const float* W3    = (const float*)d_in[6];
    const float* b3    = (const float*)d_in[7];
    const float* eps   = (const float*)d_in[8];
    const float* lin_w = (const float*)d_in[9];
    const float* lin_b = (const float*)d_in[10];
    const int* inner_src = (const int*)d_in[11];
    const int* inner_dst = (const int*)d_in[12];
    const int* fwd_src   = (const int*)d_in[13];
    const int* fwd_dst   = (const int*)d_in[14];
    const int* bwd_src   = (const int*)d_in[15];
    const int* bwd_dst   = (const int*)d_in[16];
    const int* bidx      = (const int*)d_in[17];

    float* X  = (float*)d_ws;                                 // NND*64 f32
    float* PL = X + (size_t)NND * D;                          // NG*64 f32
    unsigned short* H1h = (unsigned short*)(PL + NG * D);     // [P][256]
    unsigned short* H1l = H1h + (size_t)P * H;
    unsigned short* H2h = H1l + (size_t)P * H;                // [P][256]
    unsigned short* H2l = H2h + (size_t)P * H;
    unsigned short* w1h = H2l + (size_t)P * H;                // [4][256][96]
    unsigned short* w1l = w1h + (size_t)4 * H * KP1;
    unsigned short* w2h = w1l + (size_t)4 * H * KP1;          // [4][256][256]
    unsigned short* w2l = w2h + (size_t)4 * H * H;
    unsigned short* w3h = w2l + (size_t)4 * H * H;            // [4][64][256]
    unsigned short* w3l = w3h + (size_t)4 * D * H;
    int* deg      = (int*)(w3l + (size_t)4 * D * H);          // NSETS*P
    int* rowstart = deg + (size_t)NSETS * P;                  // NSETS*RSP
    int* rank     = rowstart + (size_t)NSETS * RSP;           // NSETS*EDG
    int* elist    = rank + (size_t)NSETS * EDG;               // NSETS*EDG

    // ---- init X + zero deg/PL
    {
        int tot = NND * D + NSETS * P + NG * D;
        k_init_x<<<(tot + 255) / 256, 256, 0, stream>>>(x0, X, deg, PL);
    }
    // ---- weight prep
    {
        int tot = 4 * H * KP1 + 4 * H * H + 4 * D * H;
        k_wsplit_all<<<(tot + 255) / 256, 256, 0, stream>>>(W1, W2, W3, w1h, w1l, w2h, w2l, w3h, w3l);
    }
    // ---- CSR build
    k_csr_hist<<<(NSETS * EDG) / 256, 256, 0, stream>>>(inner_dst, fwd_dst, bwd_dst, deg, rank);
    k_csr_scan<<<NSETS, 1024, 0, stream>>>(deg, rowstart);
    k_csr_scatter<<<(NSETS * EDG) / 256, 256, 0, stream>>>(inner_src, inner_dst, fwd_src, fwd_dst,
                                                           bwd_src, bwd_dst, rowstart, rank, elist);

    auto mlp23 = [&](int set, int gbase_out) {
        k_gemm_big<<<dim3(H / 128, P / 128), 512, 0, stream>>>(
            H1h, H1l, H,
            w2h + (size_t)set * H * H, w2l + (size_t)set * H * H, H,
            b2 + set * H, H2h, H2l, H);
        k_gemm_sm<<<dim3(1, P / 64), 256, 0, stream>>>(
            H2h, H2l, H,
            w3h + (size_t)set * D * H, w3l + (size_t)set * D * H, H,
            b3 + set * D, X + (size_t)gbase_out * D, D);
    };
    auto conv = [&](int t, int dst_gbase, int src_gbase, int ei, int set) {
        k_conv1<<<P / 64, 512, 0, stream>>>(
            X, stat, elist + (size_t)t * EDG, rowstart + (size_t)t * RSP,
            dst_gbase, src_gbase, eps, ei,
            w1h + (size_t)set * H * KP1, w1l + (size_t)set * H * KP1,
            b1 + set * H, H1h, H1l);
        mlp23(set, dst_gbase);
    };
    auto node_dnn = [&](int gbase) {
        k_conv1<<<P / 64, 512, 0, stream>>>(
            X, stat, nullptr, nullptr,
            gbase, gbase, eps, -1,
            w1h + (size_t)3 * H * KP1, w1l + (size_t)3 * H * KP1,
            b1 + 3 * H, H1h, H1l);
        mlp23(3, gbase);
    };

    // forward pass
    for (int il = 0; il < NLAYERS; ++il) {
        int s0 = il * P;
        conv(il, s0, s0, 0, 0);                       // inner conv
        if (il == NLAYERS - 1) continue;
        conv(5 + il, s0 + P, s0, 1, 1);               // fwd conv
        node_dnn(s0 + P);
    }
    // backward pass
    for (int il = NLAYERS - 1; il >= 1; --il) {
        int s0 = (il - 1) * P;
        conv(9 + (il - 1), s0, s0 + P, 2, 2);         // bwd conv
        conv(il - 1, s0, s0, 0, 0);                   // inner conv
        node_dnn(s0);
    }

    k_pool2<<<NND / PROWS, 256, 0, stream>>>(X, bidx, PL);
    k_final<<<1, 64, 0, stream>>>(PL, lin_w, lin_b, (float*)d_out);
}

// Round 12
// 2080.662 us; speedup vs baseline: 1.1683x; 1.1683x over previous
//
#include <hip/hip_runtime.h>

#define P 16384
#define NLAYERS 5
#define NND 98304          // P*(NLAYERS+1)
#define D 64
#define S 16
#define F 80               // D+S
#define KP1 96             // K of layer-1 GEMM padded to 32
#define H 256
#define EDG 262144         // 1<<18
#define NG 64
#define NSETS 13           // 5 inner + 4 fwd + 4 bwd
#define RSP 16385          // rowstart pitch (P+1)
#define LDP 40             // LDS K-stride for 32-chunks (80B rows, <=2-way aliasing)

typedef __attribute__((ext_vector_type(8))) short s16x8;
typedef __attribute__((ext_vector_type(4))) float f32x4;

// ---------------------------------------------------------------- utilities
__device__ __forceinline__ void fatomic_add(float* p, float v) {
    unsafeAtomicAdd(p, v);
}
__device__ __forceinline__ unsigned short bf16_rne(float x) {
    unsigned int u = __float_as_uint(x);
    unsigned int r = u + 0x7fffu + ((u >> 16) & 1u);
    return (unsigned short)(r >> 16);
}
__device__ __forceinline__ float bf16_to_f(unsigned short b) {
    return __uint_as_float(((unsigned int)b) << 16);
}

// ---------------------------------------------------------------- init X + zero deg + zero PL
__global__ void k_init_x(const float* __restrict__ x0, float* __restrict__ X,
                         int* __restrict__ deg, float* __restrict__ PL) {
    int idx = blockIdx.x * blockDim.x + threadIdx.x;
    if (idx < NND * D) {
        int row = idx >> 6, f = idx & 63;
        X[idx] = (f == 0) ? x0[row] : 0.0f;
        return;
    }
    int r = idx - NND * D;
    if (r < NSETS * P) { deg[r] = 0; return; }
    r -= NSETS * P;
    if (r < NG * D) PL[r] = 0.0f;
}

// ---------------------------------------------------------------- weight transpose + split (all 3 layers)
__global__ void k_wsplit_all(const float* __restrict__ W1, const float* __restrict__ W2,
                             const float* __restrict__ W3,
                             unsigned short* __restrict__ w1h, unsigned short* __restrict__ w1l,
                             unsigned short* __restrict__ w2h, unsigned short* __restrict__ w2l,
                             unsigned short* __restrict__ w3h, unsigned short* __restrict__ w3l) {
    const int n1 = 4 * H * KP1, n2 = 4 * H * H, n3 = 4 * D * H;
    int idx = blockIdx.x * blockDim.x + threadIdx.x;
    const float* W; unsigned short *h, *l; int K, N, Kp, i;
    if (idx < n1)              { W = W1; h = w1h; l = w1l; K = F; N = H; Kp = KP1; i = idx; }
    else if (idx < n1 + n2)    { W = W2; h = w2h; l = w2l; K = H; N = H; Kp = H;   i = idx - n1; }
    else if (idx < n1 + n2 + n3){ W = W3; h = w3h; l = w3l; K = H; N = D; Kp = H;  i = idx - n1 - n2; }
    else return;
    int set = i / (N * Kp), rem = i - set * (N * Kp);
    int n = rem / Kp, kp = rem - n * Kp;
    float v = (kp < K) ? W[(size_t)set * K * N + (size_t)kp * N + n] : 0.0f;
    unsigned short hh = bf16_rne(v);
    h[i] = hh;
    l[i] = bf16_rne(v - bf16_to_f(hh));
}

// ---------------------------------------------------------------- CSR build (batched, 13 sets)
__device__ __forceinline__ const int* set_ptr(int t, const int* inner, const int* fwd,
                                              const int* bwd) {
    if (t < 5) return inner + (size_t)t * EDG;
    if (t < 9) return fwd + (size_t)(t - 5) * EDG;
    return bwd + (size_t)(t - 9) * EDG;
}

__global__ void k_csr_hist(const int* __restrict__ inner_dst, const int* __restrict__ fwd_dst,
                           const int* __restrict__ bwd_dst, int* __restrict__ deg,
                           int* __restrict__ rank) {
    int idx = blockIdx.x * blockDim.x + threadIdx.x;
    if (idx >= NSETS * EDG) return;
    int t = idx >> 18, e = idx & (EDG - 1);
    const int* dstp = set_ptr(t, inner_dst, fwd_dst, bwd_dst);
    rank[idx] = atomicAdd(&deg[t * P + dstp[e]], 1);
}

__global__ __launch_bounds__(1024) void k_csr_scan(const int* __restrict__ deg,
                                                   int* __restrict__ rowstart) {
    __shared__ int part[1024];
    int t = blockIdx.x;
    const int* d = deg + t * P;
    int* rs = rowstart + (size_t)t * RSP;
    int tid = threadIdx.x;
    int base = tid * 16;
    int loc[16], sum = 0;
#pragma unroll
    for (int i = 0; i < 16; ++i) { loc[i] = sum; sum += d[base + i]; }
    part[tid] = sum;
    __syncthreads();
    for (int off = 1; off < 1024; off <<= 1) {
        int v = (tid >= off) ? part[tid - off] : 0;
        __syncthreads();
        part[tid] += v;
        __syncthreads();
    }
    int pre = tid ? part[tid - 1] : 0;
#pragma unroll
    for (int i = 0; i < 16; ++i) rs[base + i] = pre + loc[i];
    if (tid == 1023) rs[P] = pre + sum;
}

__global__ void k_csr_scatter(const int* __restrict__ inner_src, const int* __restrict__ inner_dst,
                              const int* __restrict__ fwd_src, const int* __restrict__ fwd_dst,
                              const int* __restrict__ bwd_src, const int* __restrict__ bwd_dst,
                              const int* __restrict__ rowstart, const int* __restrict__ rank,
                              int* __restrict__ elist) {
    int idx = blockIdx.x * blockDim.x + threadIdx.x;
    if (idx >= NSETS * EDG) return;
    int t = idx >> 18, e = idx & (EDG - 1);
    const int* srcp = set_ptr(t, inner_src, fwd_src, bwd_src);
    const int* dstp = set_ptr(t, inner_dst, fwd_dst, bwd_dst);
    int dv = dstp[e];
    elist[(size_t)t * EDG + rowstart[(size_t)t * RSP + dv] + rank[idx]] = srcp[e];
}

// ---------------------------------------------------------------- gather conv input (wave per node) — R9 proven
__global__ __launch_bounds__(256) void k_gather_T(const float* __restrict__ X,
                                                  const float* __restrict__ st,
                                                  const int* __restrict__ elist,
                                                  const int* __restrict__ rowstart,
                                                  unsigned short* __restrict__ Th,
                                                  unsigned short* __restrict__ Tl,
                                                  int dst_gbase, int src_gbase,
                                                  const float* __restrict__ eps, int ei) {
    int wv = threadIdx.x >> 6, l = threadIdx.x & 63;
    int v = blockIdx.x * 4 + wv;
    int beg = rowstart[v], end = rowstart[v + 1];
    float scale = 1.0f + eps[ei];
    int g = dst_gbase + v;
    float accX = X[(size_t)g * D + l] * scale;
    float accS = (l < S) ? st[(size_t)g * S + l] * scale : 0.0f;
    for (int i = beg; i < end; ++i) {
        int s = src_gbase + elist[i];            // wave-uniform load
        accX += X[(size_t)s * D + l];
        if (l < S) accS += st[(size_t)s * S + l];
    }
    unsigned short hx = bf16_rne(accX);
    Th[(size_t)v * KP1 + l] = hx;
    Tl[(size_t)v * KP1 + l] = bf16_rne(accX - bf16_to_f(hx));
    if (l < 32) {
        float vs = (l < S) ? accS : 0.0f;        // cols 80..95 = zero pad
        unsigned short hs = bf16_rne(vs);
        Th[(size_t)v * KP1 + D + l] = hs;
        Tl[(size_t)v * KP1 + D + l] = (l < S) ? bf16_rne(vs - bf16_to_f(hs)) : (unsigned short)0;
    }
}

// ---------------------------------------------------------------- CV fragment loader (X||static||0 -> split bf16)
__device__ __forceinline__ void load_cv(const float* __restrict__ X, const float* __restrict__ st,
                                        int g, int k, s16x8& h8, s16x8& l8) {
    float vv[8];
    if (k < D) {
        float4 a = *(const float4*)&X[(size_t)g * D + k];
        float4 b = *(const float4*)&X[(size_t)g * D + k + 4];
        vv[0]=a.x; vv[1]=a.y; vv[2]=a.z; vv[3]=a.w;
        vv[4]=b.x; vv[5]=b.y; vv[6]=b.z; vv[7]=b.w;
    } else if (k < F) {
        float4 a = *(const float4*)&st[(size_t)g * S + (k - D)];
        float4 b = *(const float4*)&st[(size_t)g * S + (k - D) + 4];
        vv[0]=a.x; vv[1]=a.y; vv[2]=a.z; vv[3]=a.w;
        vv[4]=b.x; vv[5]=b.y; vv[6]=b.z; vv[7]=b.w;
    } else {
#pragma unroll
        for (int j = 0; j < 8; ++j) vv[j] = 0.0f;
    }
#pragma unroll
    for (int j = 0; j < 8; ++j) {
        unsigned short hh = bf16_rne(vv[j]);
        h8[j] = (short)hh;
        l8[j] = (short)bf16_rne(vv[j] - bf16_to_f(hh));
    }
}

// ---------------------------------------------------------------- direct-fragment GEMM (no LDS, no barriers)
// 8 waves as 2(m) x 4(n); block tile 128x128; grid (N/128, P/128).
// A: split planes (CV=false, lda) or fp32 X||st||0 (CV=true, gbase). B: Wt[N][Kp] split planes.
// Out: split planes Ch/Cl, ldc.
template<bool CV>
__global__ __launch_bounds__(512) void k_gemm_d(
    const unsigned short* __restrict__ Ahp, const unsigned short* __restrict__ Alp, int lda,
    const float* __restrict__ Xsrc, const float* __restrict__ stsrc, int gbase,
    const unsigned short* __restrict__ Wh, const unsigned short* __restrict__ Wl, int Kp,
    const float* __restrict__ bias,
    unsigned short* __restrict__ Ch, unsigned short* __restrict__ Cl, int ldc)
{
    int tid = threadIdx.x;
    int lane = tid & 63, wid = tid >> 6;
    int wm = wid >> 2, wn = wid & 3;                  // 2 x 4 wave grid, wave tile 64x32
    int la = lane & 15, lg = lane >> 4;
    int m0 = blockIdx.y * 128 + wm * 64;
    int n0 = blockIdx.x * 128 + wn * 32;

    f32x4 acc[4][2] = {};

    for (int k0 = 0; k0 < Kp; k0 += 32) {
        int kf = k0 + lg * 8;
        s16x8 ah[4], al[4], bh[2], bl[2];
#pragma unroll
        for (int m = 0; m < 4; ++m) {
            int row = m0 + m * 16 + la;
            if (!CV) {
                size_t o = (size_t)row * lda + kf;
                ah[m] = *(const s16x8*)&Ahp[o];
                al[m] = *(const s16x8*)&Alp[o];
            } else {
                load_cv(Xsrc, stsrc, gbase + row, kf, ah[m], al[m]);
            }
        }
#pragma unroll
        for (int n = 0; n < 2; ++n) {
            int col = n0 + n * 16 + la;
            size_t o = (size_t)col * Kp + kf;
            bh[n] = *(const s16x8*)&Wh[o];
            bl[n] = *(const s16x8*)&Wl[o];
        }
#pragma unroll
        for (int m = 0; m < 4; ++m)
#pragma unroll
            for (int n = 0; n < 2; ++n) {
                acc[m][n] = __builtin_amdgcn_mfma_f32_16x16x32_bf16(ah[m], bh[n], acc[m][n], 0, 0, 0);
                acc[m][n] = __builtin_amdgcn_mfma_f32_16x16x32_bf16(ah[m], bl[n], acc[m][n], 0, 0, 0);
                acc[m][n] = __builtin_amdgcn_mfma_f32_16x16x32_bf16(al[m], bh[n], acc[m][n], 0, 0, 0);
            }
    }

#pragma unroll
    for (int n = 0; n < 2; ++n) {
        int col = n0 + n * 16 + la;
        float bv = bias[col];
#pragma unroll
        for (int m = 0; m < 4; ++m) {
            int row = m0 + m * 16 + lg * 4;
#pragma unroll
            for (int r = 0; r < 4; ++r) {
                float v = fmaxf(acc[m][n][r] + bv, 0.0f);
                size_t o = (size_t)(row + r) * ldc + col;
                unsigned short hh = bf16_rne(v);
                Ch[o] = hh;
                Cl[o] = bf16_rne(v - bf16_to_f(hh));
            }
        }
    }
}

// ---------------------------------------------------------------- GEMM3 (64x64 tile, 4 waves, LDS) -> fp32 X — R9 proven
__global__ __launch_bounds__(256) void k_gemm_sm(
    const unsigned short* __restrict__ Ahp, const unsigned short* __restrict__ Alp, int lda,
    const unsigned short* __restrict__ Wh, const unsigned short* __restrict__ Wl, int Kp,
    const float* __restrict__ bias, float* __restrict__ Cf, int ldc)
{
    __shared__ unsigned short Ah[64][LDP], Al[64][LDP];
    __shared__ unsigned short Bh[64][LDP], Bl[64][LDP];

    int tid = threadIdx.x;
    int lane = tid & 63, wid = tid >> 6;
    int wm = wid >> 1, wn = wid & 1;           // 2 x 2, wave tile 32x32
    int m0 = blockIdx.y * 64;

    f32x4 acc[2][2] = {};

    int sr = tid >> 2;
    int sc = (tid & 3) * 8;
    int la = lane & 15, lg = lane >> 4;

    for (int k0 = 0; k0 < Kp; k0 += 32) {
        size_t oa = (size_t)(m0 + sr) * lda + k0 + sc;
        *(s16x8*)&Ah[sr][sc] = *(const s16x8*)&Ahp[oa];
        *(s16x8*)&Al[sr][sc] = *(const s16x8*)&Alp[oa];
        size_t ob = (size_t)sr * Kp + k0 + sc;
        *(s16x8*)&Bh[sr][sc] = *(const s16x8*)&Wh[ob];
        *(s16x8*)&Bl[sr][sc] = *(const s16x8*)&Wl[ob];
        __syncthreads();

        int kf = lg * 8;
        s16x8 ah[2], al[2], bh[2], bl[2];
#pragma unroll
        for (int m = 0; m < 2; ++m) {
            int r = wm * 32 + m * 16 + la;
            ah[m] = *(const s16x8*)&Ah[r][kf];
            al[m] = *(const s16x8*)&Al[r][kf];
        }
#pragma unroll
        for (int n = 0; n < 2; ++n) {
            int r = wn * 32 + n * 16 + la;
            bh[n] = *(const s16x8*)&Bh[r][kf];
            bl[n] = *(const s16x8*)&Bl[r][kf];
        }
#pragma unroll
        for (int m = 0; m < 2; ++m)
#pragma unroll
            for (int n = 0; n < 2; ++n) {
                acc[m][n] = __builtin_amdgcn_mfma_f32_16x16x32_bf16(ah[m], bh[n], acc[m][n], 0, 0, 0);
                acc[m][n] = __builtin_amdgcn_mfma_f32_16x16x32_bf16(ah[m], bl[n], acc[m][n], 0, 0, 0);
                acc[m][n] = __builtin_amdgcn_mfma_f32_16x16x32_bf16(al[m], bh[n], acc[m][n], 0, 0, 0);
            }
        __syncthreads();
    }

#pragma unroll
    for (int n = 0; n < 2; ++n) {
        int col = wn * 32 + n * 16 + la;
        float bv = bias[col];
#pragma unroll
        for (int m = 0; m < 2; ++m) {
            int row = m0 + wm * 32 + m * 16 + lg * 4;
#pragma unroll
            for (int r = 0; r < 4; ++r) {
                Cf[(size_t)(row + r) * ldc + col] = fmaxf(acc[m][n][r] + bv, 0.0f);
            }
        }
    }
}

// ---------------------------------------------------------------- two-stage pooling
#define PROWS 1024
__global__ __launch_bounds__(256) void k_pool2(const float* __restrict__ X,
                                               const int* __restrict__ bidx,
                                               float* __restrict__ PL) {
    __shared__ float lds[NG * D];
    int tid = threadIdx.x;
    for (int i = tid; i < NG * D; i += 256) lds[i] = 0.0f;
    __syncthreads();
    int base = blockIdx.x * PROWS;
    int f = tid & 63, rg = tid >> 6;
    for (int r = base + rg; r < base + PROWS; r += 4) {
        int g = bidx[r];
        atomicAdd(&lds[g * D + f], X[(size_t)r * D + f]);
    }
    __syncthreads();
    for (int i = tid; i < NG * D; i += 256) {
        float v = lds[i];
        if (v != 0.0f) fatomic_add(&PL[i], v);
    }
}

// ---------------------------------------------------------------- final linear head
__global__ void k_final(const float* __restrict__ pooled, const float* __restrict__ lin_w,
                        const float* __restrict__ lin_b, float* __restrict__ out) {
    int g = threadIdx.x;
    if (g >= NG) return;
    float acc = lin_b[0];
#pragma unroll
    for (int d2 = 0; d2 < D; ++d2) acc += pooled[g * D + d2] * lin_w[d2];
    out[g] = fmaxf(acc, 0.0f);
}

// ---------------------------------------------------------------- launch
extern "C" void kernel_launch(void* const* d_in, const int* in_sizes, int n_in,
                              void* d_out, int out_size, void* d_ws, size_t ws_size,
                              hipStream_t stream) {
    const float* x0    = (const float*)d_in[0];
    const float* stat  = (const float*)d_in[1];
    const float* W1    = (const float*)d_in[2];
    const float* b1    = (const float*)d_in[3];
    const float* W2    = (const float*)d_in[4];
    const float* b2    = (const float*)d_in[5];
    const float* W3    = (const float*)d_in[6];
    const float* b3    = (const float*)d_in[7];
    const float* eps   = (const float*)d_in[8];
    const float* lin_w = (const float*)d_in[9];
    const float* lin_b = (const float*)d_in[10];
    const int* inner_src = (const int*)d_in[11];
    const int* inner_dst = (const int*)d_in[12];
    const int* fwd_src   = (const int*)d_in[13];
    const int* fwd_dst   = (const int*)d_in[14];
    const int* bwd_src   = (const int*)d_in[15];
    const int* bwd_dst   = (const int*)d_in[16];
    const int* bidx      = (const int*)d_in[17];

    float* X  = (float*)d_ws;                                 // NND*64 f32
    float* PL = X + (size_t)NND * D;                          // NG*64 f32
    unsigned short* Th  = (unsigned short*)(PL + NG * D);     // [P][96]
    unsigned short* Tl  = Th  + (size_t)P * KP1;
    unsigned short* H1h = Tl  + (size_t)P * KP1;              // [P][256]
    unsigned short* H1l = H1h + (size_t)P * H;
    unsigned short* H2h = H1l + (size_t)P * H;                // [P][256]
    unsigned short* H2l = H2h + (size_t)P * H;
    unsigned short* w1h = H2l + (size_t)P * H;                // [4][256][96]
    unsigned short* w1l = w1h + (size_t)4 * H * KP1;
    unsigned short* w2h = w1l + (size_t)4 * H * KP1;          // [4][256][256]
    unsigned short* w2l = w2h + (size_t)4 * H * H;
    unsigned short* w3h = w2l + (size_t)4 * H * H;            // [4][64][256]
    unsigned short* w3l = w3h + (size_t)4 * D * H;
    int* deg      = (int*)(w3l + (size_t)4 * D * H);          // NSETS*P
    int* rowstart = deg + (size_t)NSETS * P;                  // NSETS*RSP
    int* rank     = rowstart + (size_t)NSETS * RSP;           // NSETS*EDG
    int* elist    = rank + (size_t)NSETS * EDG;               // NSETS*EDG

    // ---- init X + zero deg/PL
    {
        int tot = NND * D + NSETS * P + NG * D;
        k_init_x<<<(tot + 255) / 256, 256, 0, stream>>>(x0, X, deg, PL);
    }
    // ---- weight prep
    {
        int tot = 4 * H * KP1 + 4 * H * H + 4 * D * H;
        k_wsplit_all<<<(tot + 255) / 256, 256, 0, stream>>>(W1, W2, W3, w1h, w1l, w2h, w2l, w3h, w3l);
    }
    // ---- CSR build
    k_csr_hist<<<(NSETS * EDG) / 256, 256, 0, stream>>>(inner_dst, fwd_dst, bwd_dst, deg, rank);
    k_csr_scan<<<NSETS, 1024, 0, stream>>>(deg, rowstart);
    k_csr_scatter<<<(NSETS * EDG) / 256, 256, 0, stream>>>(inner_src, inner_dst, fwd_src, fwd_dst,
                                                           bwd_src, bwd_dst, rowstart, rank, elist);

    auto mlp23 = [&](int set, int gbase_out) {
        k_gemm_d<false><<<dim3(H / 128, P / 128), 512, 0, stream>>>(
            H1h, H1l, H, nullptr, nullptr, 0,
            w2h + (size_t)set * H * H, w2l + (size_t)set * H * H, H,
            b2 + set * H, H2h, H2l, H);
        k_gemm_sm<<<dim3(1, P / 64), 256, 0, stream>>>(
            H2h, H2l, H,
            w3h + (size_t)set * D * H, w3l + (size_t)set * D * H, H,
            b3 + set * D, X + (size_t)gbase_out * D, D);
    };
    auto conv = [&](int t, int dst_gbase, int src_gbase, int ei, int set) {
        k_gather_T<<<P / 4, 256, 0, stream>>>(
            X, stat, elist + (size_t)t * EDG, rowstart + (size_t)t * RSP,
            Th, Tl, dst_gbase, src_gbase, eps, ei);
        k_gemm_d<false><<<dim3(H / 128, P / 128), 512, 0, stream>>>(
            Th, Tl, KP1, nullptr, nullptr, 0,
            w1h + (size_t)set * H * KP1, w1l + (size_t)set * H * KP1, KP1,
            b1 + set * H, H1h, H1l, H);
        mlp23(set, dst_gbase);
    };
    auto node_dnn = [&](int gbase) {
        k_gemm_d<true><<<dim3(H / 128, P / 128), 512, 0, stream>>>(
            nullptr, nullptr, 0, X, stat, gbase,
            w1h + (size_t)3 * H * KP1, w1l + (size_t)3 * H * KP1, KP1,
            b1 + 3 * H, H1h, H1l, H);
        mlp23(3, gbase);
    };

    // forward pass
    for (int il = 0; il < NLAYERS; ++il) {
        int s0 = il * P;
        conv(il, s0, s0, 0, 0);                       // inner conv
        if (il == NLAYERS - 1) continue;
        conv(5 + il, s0 + P, s0, 1, 1);               // fwd conv
        node_dnn(s0 + P);
    }
    // backward pass
    for (int il = NLAYERS - 1; il >= 1; --il) {
        int s0 = (il - 1) * P;
        conv(9 + (il - 1), s0, s0 + P, 2, 2);         // bwd conv
        conv(il - 1, s0, s0, 0, 0);                   // inner conv
        node_dnn(s0);
    }

    k_pool2<<<NND / PROWS, 256, 0, stream>>>(X, bidx, PL);
    k_final<<<1, 64, 0, stream>>>(PL, lin_w, lin_b, (float*)d_out);
}

// Round 13
// 1555.761 us; speedup vs baseline: 1.5625x; 1.3374x over previous
//
#include <hip/hip_runtime.h>

#define P 16384
#define NLAYERS 5
#define NND 98304          // P*(NLAYERS+1)
#define D 64
#define S 16
#define F 80               // D+S
#define KP1 96             // K of layer-1 GEMM padded to 32
#define H 256
#define EDG 262144         // 1<<18
#define NG 64
#define NSETS 13           // 5 inner + 4 fwd + 4 bwd
#define RSP 16385          // rowstart pitch (P+1)
#define LDP 40             // LDS K-stride for 32-chunks (80B rows, <=2-way aliasing)
#define LH2 264            // H2 LDS row stride (256+8)

typedef __attribute__((ext_vector_type(8))) short s16x8;
typedef __attribute__((ext_vector_type(4))) float f32x4;

// ---------------------------------------------------------------- utilities
__device__ __forceinline__ void fatomic_add(float* p, float v) {
    unsafeAtomicAdd(p, v);
}
__device__ __forceinline__ unsigned short bf16_rne(float x) {
    unsigned int u = __float_as_uint(x);
    unsigned int r = u + 0x7fffu + ((u >> 16) & 1u);
    return (unsigned short)(r >> 16);
}
__device__ __forceinline__ float bf16_to_f(unsigned short b) {
    return __uint_as_float(((unsigned int)b) << 16);
}

// ---------------------------------------------------------------- init X + zero deg + zero PL
__global__ void k_init_x(const float* __restrict__ x0, float* __restrict__ X,
                         int* __restrict__ deg, float* __restrict__ PL) {
    int idx = blockIdx.x * blockDim.x + threadIdx.x;
    if (idx < NND * D) {
        int row = idx >> 6, f = idx & 63;
        X[idx] = (f == 0) ? x0[row] : 0.0f;
        return;
    }
    int r = idx - NND * D;
    if (r < NSETS * P) { deg[r] = 0; return; }
    r -= NSETS * P;
    if (r < NG * D) PL[r] = 0.0f;
}

// ---------------------------------------------------------------- weight transpose + split (all 3 layers)
__global__ void k_wsplit_all(const float* __restrict__ W1, const float* __restrict__ W2,
                             const float* __restrict__ W3,
                             unsigned short* __restrict__ w1h, unsigned short* __restrict__ w1l,
                             unsigned short* __restrict__ w2h, unsigned short* __restrict__ w2l,
                             unsigned short* __restrict__ w3h, unsigned short* __restrict__ w3l) {
    const int n1 = 4 * H * KP1, n2 = 4 * H * H, n3 = 4 * D * H;
    int idx = blockIdx.x * blockDim.x + threadIdx.x;
    const float* W; unsigned short *h, *l; int K, N, Kp, i;
    if (idx < n1)              { W = W1; h = w1h; l = w1l; K = F; N = H; Kp = KP1; i = idx; }
    else if (idx < n1 + n2)    { W = W2; h = w2h; l = w2l; K = H; N = H; Kp = H;   i = idx - n1; }
    else if (idx < n1 + n2 + n3){ W = W3; h = w3h; l = w3l; K = H; N = D; Kp = H;  i = idx - n1 - n2; }
    else return;
    int set = i / (N * Kp), rem = i - set * (N * Kp);
    int n = rem / Kp, kp = rem - n * Kp;
    float v = (kp < K) ? W[(size_t)set * K * N + (size_t)kp * N + n] : 0.0f;
    unsigned short hh = bf16_rne(v);
    h[i] = hh;
    l[i] = bf16_rne(v - bf16_to_f(hh));
}

// ---------------------------------------------------------------- CSR build (batched, 13 sets)
__device__ __forceinline__ const int* set_ptr(int t, const int* inner, const int* fwd,
                                              const int* bwd) {
    if (t < 5) return inner + (size_t)t * EDG;
    if (t < 9) return fwd + (size_t)(t - 5) * EDG;
    return bwd + (size_t)(t - 9) * EDG;
}

__global__ void k_csr_hist(const int* __restrict__ inner_dst, const int* __restrict__ fwd_dst,
                           const int* __restrict__ bwd_dst, int* __restrict__ deg,
                           int* __restrict__ rank) {
    int idx = blockIdx.x * blockDim.x + threadIdx.x;
    if (idx >= NSETS * EDG) return;
    int t = idx >> 18, e = idx & (EDG - 1);
    const int* dstp = set_ptr(t, inner_dst, fwd_dst, bwd_dst);
    rank[idx] = atomicAdd(&deg[t * P + dstp[e]], 1);
}

__global__ __launch_bounds__(1024) void k_csr_scan(const int* __restrict__ deg,
                                                   int* __restrict__ rowstart) {
    __shared__ int part[1024];
    int t = blockIdx.x;
    const int* d = deg + t * P;
    int* rs = rowstart + (size_t)t * RSP;
    int tid = threadIdx.x;
    int base = tid * 16;
    int loc[16], sum = 0;
#pragma unroll
    for (int i = 0; i < 16; ++i) { loc[i] = sum; sum += d[base + i]; }
    part[tid] = sum;
    __syncthreads();
    for (int off = 1; off < 1024; off <<= 1) {
        int v = (tid >= off) ? part[tid - off] : 0;
        __syncthreads();
        part[tid] += v;
        __syncthreads();
    }
    int pre = tid ? part[tid - 1] : 0;
#pragma unroll
    for (int i = 0; i < 16; ++i) rs[base + i] = pre + loc[i];
    if (tid == 1023) rs[P] = pre + sum;
}

__global__ void k_csr_scatter(const int* __restrict__ inner_src, const int* __restrict__ inner_dst,
                              const int* __restrict__ fwd_src, const int* __restrict__ fwd_dst,
                              const int* __restrict__ bwd_src, const int* __restrict__ bwd_dst,
                              const int* __restrict__ rowstart, const int* __restrict__ rank,
                              int* __restrict__ elist) {
    int idx = blockIdx.x * blockDim.x + threadIdx.x;
    if (idx >= NSETS * EDG) return;
    int t = idx >> 18, e = idx & (EDG - 1);
    const int* srcp = set_ptr(t, inner_src, fwd_src, bwd_src);
    const int* dstp = set_ptr(t, inner_dst, fwd_dst, bwd_dst);
    int dv = dstp[e];
    elist[(size_t)t * EDG + rowstart[(size_t)t * RSP + dv] + rank[idx]] = srcp[e];
}

// ---------------------------------------------------------------- gather conv input (wave per node) — proven
__global__ __launch_bounds__(256) void k_gather_T(const float* __restrict__ X,
                                                  const float* __restrict__ st,
                                                  const int* __restrict__ elist,
                                                  const int* __restrict__ rowstart,
                                                  unsigned short* __restrict__ Th,
                                                  unsigned short* __restrict__ Tl,
                                                  int dst_gbase, int src_gbase,
                                                  const float* __restrict__ eps, int ei) {
    int wv = threadIdx.x >> 6, l = threadIdx.x & 63;
    int v = blockIdx.x * 4 + wv;
    int beg = rowstart[v], end = rowstart[v + 1];
    float scale = 1.0f + eps[ei];
    int g = dst_gbase + v;
    float accX = X[(size_t)g * D + l] * scale;
    float accS = (l < S) ? st[(size_t)g * S + l] * scale : 0.0f;
    for (int i = beg; i < end; ++i) {
        int s = src_gbase + elist[i];            // wave-uniform load
        accX += X[(size_t)s * D + l];
        if (l < S) accS += st[(size_t)s * S + l];
    }
    unsigned short hx = bf16_rne(accX);
    Th[(size_t)v * KP1 + l] = hx;
    Tl[(size_t)v * KP1 + l] = bf16_rne(accX - bf16_to_f(hx));
    if (l < 32) {
        float vs = (l < S) ? accS : 0.0f;        // cols 80..95 = zero pad
        unsigned short hs = bf16_rne(vs);
        Th[(size_t)v * KP1 + D + l] = hs;
        Tl[(size_t)v * KP1 + D + l] = (l < S) ? bf16_rne(vs - bf16_to_f(hs)) : (unsigned short)0;
    }
}

// ---------------------------------------------------------------- GEMM1 (128x128, 8 waves, LDS) — R8-proven
// C(split planes) = relu(A @ Wt^T + bias). A: split planes (CV=false) or fp32 X||st||0 (CV=true).
template<bool CV>
__global__ __launch_bounds__(512) void k_gemm_big(
    const unsigned short* __restrict__ Ahp, const unsigned short* __restrict__ Alp, int lda,
    const float* __restrict__ Xsrc, const float* __restrict__ stsrc, int gbase,
    const unsigned short* __restrict__ Wh, const unsigned short* __restrict__ Wl, int Kp,
    const float* __restrict__ bias,
    unsigned short* __restrict__ Ch, unsigned short* __restrict__ Cl, int ldc)
{
    __shared__ unsigned short Ah[128][LDP], Al[128][LDP];
    __shared__ unsigned short Bh[128][LDP], Bl[128][LDP];   // 40 KB total

    int tid = threadIdx.x;
    int lane = tid & 63, wid = tid >> 6;       // 8 waves
    int wm = wid >> 2, wn = wid & 3;           // 2 x 4, wave tile 64x32
    int m0 = blockIdx.y * 128, n0 = blockIdx.x * 128;

    f32x4 acc[4][2] = {};

    int ar = tid >> 2;
    int ac = (tid & 3) * 8;
    int la = lane & 15, lg = lane >> 4;

    for (int k0 = 0; k0 < Kp; k0 += 32) {
        if (!CV) {
            size_t oa = (size_t)(m0 + ar) * lda + k0 + ac;
            *(s16x8*)&Ah[ar][ac] = *(const s16x8*)&Ahp[oa];
            *(s16x8*)&Al[ar][ac] = *(const s16x8*)&Alp[oa];
        } else {
            int g = gbase + m0 + ar;
            int k = k0 + ac;
            float vv[8];
            if (k < D) {
                float4 a = *(const float4*)&Xsrc[(size_t)g * D + k];
                float4 b = *(const float4*)&Xsrc[(size_t)g * D + k + 4];
                vv[0]=a.x; vv[1]=a.y; vv[2]=a.z; vv[3]=a.w;
                vv[4]=b.x; vv[5]=b.y; vv[6]=b.z; vv[7]=b.w;
            } else if (k < F) {
                float4 a = *(const float4*)&stsrc[(size_t)g * S + (k - D)];
                float4 b = *(const float4*)&stsrc[(size_t)g * S + (k - D) + 4];
                vv[0]=a.x; vv[1]=a.y; vv[2]=a.z; vv[3]=a.w;
                vv[4]=b.x; vv[5]=b.y; vv[6]=b.z; vv[7]=b.w;
            } else {
#pragma unroll
                for (int j = 0; j < 8; ++j) vv[j] = 0.0f;
            }
#pragma unroll
            for (int j = 0; j < 8; ++j) {
                unsigned short hh = bf16_rne(vv[j]);
                Ah[ar][ac + j] = hh;
                Al[ar][ac + j] = bf16_rne(vv[j] - bf16_to_f(hh));
            }
        }
        {
            size_t ob = (size_t)(n0 + ar) * Kp + k0 + ac;
            *(s16x8*)&Bh[ar][ac] = *(const s16x8*)&Wh[ob];
            *(s16x8*)&Bl[ar][ac] = *(const s16x8*)&Wl[ob];
        }
        __syncthreads();

        int kf = lg * 8;
        s16x8 ah[4], al[4], bh[2], bl[2];
#pragma unroll
        for (int m = 0; m < 4; ++m) {
            int r = wm * 64 + m * 16 + la;
            ah[m] = *(const s16x8*)&Ah[r][kf];
            al[m] = *(const s16x8*)&Al[r][kf];
        }
#pragma unroll
        for (int n = 0; n < 2; ++n) {
            int r = wn * 32 + n * 16 + la;
            bh[n] = *(const s16x8*)&Bh[r][kf];
            bl[n] = *(const s16x8*)&Bl[r][kf];
        }
#pragma unroll
        for (int m = 0; m < 4; ++m)
#pragma unroll
            for (int n = 0; n < 2; ++n) {
                acc[m][n] = __builtin_amdgcn_mfma_f32_16x16x32_bf16(ah[m], bh[n], acc[m][n], 0, 0, 0);
                acc[m][n] = __builtin_amdgcn_mfma_f32_16x16x32_bf16(ah[m], bl[n], acc[m][n], 0, 0, 0);
                acc[m][n] = __builtin_amdgcn_mfma_f32_16x16x32_bf16(al[m], bh[n], acc[m][n], 0, 0, 0);
            }
        __syncthreads();
    }

#pragma unroll
    for (int n = 0; n < 2; ++n) {
        int col = n0 + wn * 32 + n * 16 + la;
        float bv = bias[col];
#pragma unroll
        for (int m = 0; m < 4; ++m) {
            int row = m0 + wm * 64 + m * 16 + lg * 4;
#pragma unroll
            for (int r = 0; r < 4; ++r) {
                float v = fmaxf(acc[m][n][r] + bv, 0.0f);
                size_t o = (size_t)(row + r) * ldc + col;
                unsigned short hh = bf16_rne(v);
                Ch[o] = hh;
                Cl[o] = bf16_rne(v - bf16_to_f(hh));
            }
        }
    }
}

// ---------------------------------------------------------------- fused GEMM2+GEMM3 (64-row tile, 8 waves)
// X_out[64][64] = relu( relu(H1[64]@W2^T + b2) @ W3^T + b3 ); H2 tile lives in LDS only.
__global__ __launch_bounds__(512) void k_mlp23(
    const unsigned short* __restrict__ H1h, const unsigned short* __restrict__ H1l,
    const unsigned short* __restrict__ W2h, const unsigned short* __restrict__ W2l,  // [256][256]
    const float* __restrict__ b2,
    const unsigned short* __restrict__ W3h, const unsigned short* __restrict__ W3l,  // [64][256]
    const float* __restrict__ b3,
    float* __restrict__ Xout)                                                        // [P][64] slice
{
    __shared__ unsigned short A1h[64][LDP], A1l[64][LDP];      // 10.2 KB
    __shared__ unsigned short B1h[256][LDP], B1l[256][LDP];    // 41 KB (reused for W3)
    __shared__ unsigned short H2hs[64][LH2], H2ls[64][LH2];    // 67.6 KB

    int tid = threadIdx.x;
    int lane = tid & 63, wid = tid >> 6;
    int la = lane & 15, lg = lane >> 4;
    int r0 = blockIdx.x * 64;

    // ================= phase 1: H2 = relu(H1 @ W2^T + b2), all 8 waves on 64x256
    // wave wid owns cols [wid*32, wid*32+32)
    f32x4 acc[4][2] = {};
    {
        // staging maps
        int apl = tid >> 8, arem = tid & 255;
        int ar = arem >> 2, aq = (arem & 3) * 8;          // A: 1 chunk/thread
        for (int k0 = 0; k0 < H; k0 += 32) {
            // stage A (64 x 32, both planes)
            {
                const unsigned short* src = apl ? H1l : H1h;
                unsigned short (*dsth)[LDP] = apl ? A1l : A1h;
                *(s16x8*)&dsth[ar][aq] = *(const s16x8*)&src[(size_t)(r0 + ar) * H + k0 + aq];
            }
            // stage B (256 x 32, both planes): 4 chunks/thread
#pragma unroll
            for (int j = 0; j < 4; ++j) {
                int id = j * 512 + tid;
                int bpl = id >> 10, brem = id & 1023;
                int br = brem >> 2, bq = (brem & 3) * 8;
                const unsigned short* src = bpl ? W2l : W2h;
                unsigned short (*dsth)[LDP] = bpl ? B1l : B1h;
                *(s16x8*)&dsth[br][bq] = *(const s16x8*)&src[(size_t)br * H + k0 + bq];
            }
            __syncthreads();

            int kf = lg * 8;
            s16x8 ah[4], al[4], bh[2], bl[2];
#pragma unroll
            for (int m = 0; m < 4; ++m) {
                int r = m * 16 + la;
                ah[m] = *(const s16x8*)&A1h[r][kf];
                al[m] = *(const s16x8*)&A1l[r][kf];
            }
#pragma unroll
            for (int n = 0; n < 2; ++n) {
                int r = wid * 32 + n * 16 + la;
                bh[n] = *(const s16x8*)&B1h[r][kf];
                bl[n] = *(const s16x8*)&B1l[r][kf];
            }
#pragma unroll
            for (int m = 0; m < 4; ++m)
#pragma unroll
                for (int n = 0; n < 2; ++n) {
                    acc[m][n] = __builtin_amdgcn_mfma_f32_16x16x32_bf16(ah[m], bh[n], acc[m][n], 0, 0, 0);
                    acc[m][n] = __builtin_amdgcn_mfma_f32_16x16x32_bf16(ah[m], bl[n], acc[m][n], 0, 0, 0);
                    acc[m][n] = __builtin_amdgcn_mfma_f32_16x16x32_bf16(al[m], bh[n], acc[m][n], 0, 0, 0);
                }
            __syncthreads();
        }
    }
    // write H2 tile to LDS (bias + relu + split)
#pragma unroll
    for (int n = 0; n < 2; ++n) {
        int col = wid * 32 + n * 16 + la;
        float bv = b2[col];
#pragma unroll
        for (int m = 0; m < 4; ++m) {
            int row = m * 16 + lg * 4;
#pragma unroll
            for (int r = 0; r < 4; ++r) {
                float v = fmaxf(acc[m][n][r] + bv, 0.0f);
                unsigned short hh = bf16_rne(v);
                H2hs[row + r][col] = hh;
                H2ls[row + r][col] = bf16_rne(v - bf16_to_f(hh));
            }
        }
    }
    __syncthreads();

    // ================= phase 2: Xout = relu(H2 @ W3^T + b3), K=256
    // 8 waves as 2(m) x 4(n): wave tile 32 rows x 16 cols
    int wm = wid >> 2, wn = wid & 3;
    f32x4 acc2[2] = {};
    {
        int apl = tid >> 8, arem = tid & 255;
        int br = arem >> 2, bq = (arem & 3) * 8;          // B3: 1 chunk/thread (64 x 32 x 2pl)
        for (int k0 = 0; k0 < H; k0 += 32) {
            {
                const unsigned short* src = apl ? W3l : W3h;
                unsigned short (*dsth)[LDP] = apl ? B1l : B1h;
                *(s16x8*)&dsth[br][bq] = *(const s16x8*)&src[(size_t)br * H + k0 + bq];
            }
            __syncthreads();

            int kf = lg * 8;
            s16x8 ah[2], al[2], bh, bl;
#pragma unroll
            for (int m = 0; m < 2; ++m) {
                int r = wm * 32 + m * 16 + la;
                ah[m] = *(const s16x8*)&H2hs[r][k0 + kf];
                al[m] = *(const s16x8*)&H2ls[r][k0 + kf];
            }
            {
                int r = wn * 16 + la;
                bh = *(const s16x8*)&B1h[r][kf];
                bl = *(const s16x8*)&B1l[r][kf];
            }
#pragma unroll
            for (int m = 0; m < 2; ++m) {
                acc2[m] = __builtin_amdgcn_mfma_f32_16x16x32_bf16(ah[m], bh, acc2[m], 0, 0, 0);
                acc2[m] = __builtin_amdgcn_mfma_f32_16x16x32_bf16(ah[m], bl, acc2[m], 0, 0, 0);
                acc2[m] = __builtin_amdgcn_mfma_f32_16x16x32_bf16(al[m], bh, acc2[m], 0, 0, 0);
            }
            __syncthreads();
        }
    }
    {
        int col = wn * 16 + la;
        float bv = b3[col];
#pragma unroll
        for (int m = 0; m < 2; ++m) {
            int row = r0 + wm * 32 + m * 16 + lg * 4;
#pragma unroll
            for (int r = 0; r < 4; ++r) {
                Xout[(size_t)(row + r) * D + col] = fmaxf(acc2[m][r] + bv, 0.0f);
            }
        }
    }
}

// ---------------------------------------------------------------- two-stage pooling
#define PROWS 1024
__global__ __launch_bounds__(256) void k_pool2(const float* __restrict__ X,
                                               const int* __restrict__ bidx,
                                               float* __restrict__ PL) {
    __shared__ float lds[NG * D];
    int tid = threadIdx.x;
    for (int i = tid; i < NG * D; i += 256) lds[i] = 0.0f;
    __syncthreads();
    int base = blockIdx.x * PROWS;
    int f = tid & 63, rg = tid >> 6;
    for (int r = base + rg; r < base + PROWS; r += 4) {
        int g = bidx[r];
        atomicAdd(&lds[g * D + f], X[(size_t)r * D + f]);
    }
    __syncthreads();
    for (int i = tid; i < NG * D; i += 256) {
        float v = lds[i];
        if (v != 0.0f) fatomic_add(&PL[i], v);
    }
}

// ---------------------------------------------------------------- final linear head
__global__ void k_final(const float* __restrict__ pooled, const float* __restrict__ lin_w,
                        const float* __restrict__ lin_b, float* __restrict__ out) {
    int g = threadIdx.x;
    if (g >= NG) return;
    float acc = lin_b[0];
#pragma unroll
    for (int d2 = 0; d2 < D; ++d2) acc += pooled[g * D + d2] * lin_w[d2];
    out[g] = fmaxf(acc, 0.0f);
}

// ---------------------------------------------------------------- launch
extern "C" void kernel_launch(void* const* d_in, const int* in_sizes, int n_in,
                              void* d_out, int out_size, void* d_ws, size_t ws_size,
                              hipStream_t stream) {
    const float* x0    = (const float*)d_in[0];
    const float* stat  = (const float*)d_in[1];
    const float* W1    = (const float*)d_in[2];
    const float* b1    = (const float*)d_in[3];
    const float* W2    = (const float*)d_in[4];
    const float* b2    = (const float*)d_in[5];
    const float* W3    = (const float*)d_in[6];
    const float* b3    = (const float*)d_in[7];
    const float* eps   = (const float*)d_in[8];
    const float* lin_w = (const float*)d_in[9];
    const float* lin_b = (const float*)d_in[10];
    const int* inner_src = (const int*)d_in[11];
    const int* inner_dst = (const int*)d_in[12];
    const int* fwd_src   = (const int*)d_in[13];
    const int* fwd_dst   = (const int*)d_in[14];
    const int* bwd_src   = (const int*)d_in[15];
    const int* bwd_dst   = (const int*)d_in[16];
    const int* bidx      = (const int*)d_in[17];

    float* X  = (float*)d_ws;                                 // NND*64 f32
    float* PL = X + (size_t)NND * D;                          // NG*64 f32
    unsigned short* Th  = (unsigned short*)(PL + NG * D);     // [P][96]
    unsigned short* Tl  = Th  + (size_t)P * KP1;
    unsigned short* H1h = Tl  + (size_t)P * KP1;              // [P][256]
    unsigned short* H1l = H1h + (size_t)P * H;
    unsigned short* w1h = H1l + (size_t)P * H;                // [4][256][96]
    unsigned short* w1l = w1h + (size_t)4 * H * KP1;
    unsigned short* w2h = w1l + (size_t)4 * H * KP1;          // [4][256][256]
    unsigned short* w2l = w2h + (size_t)4 * H * H;
    unsigned short* w3h = w2l + (size_t)4 * H * H;            // [4][64][256]
    unsigned short* w3l = w3h + (size_t)4 * D * H;
    int* deg      = (int*)(w3l + (size_t)4 * D * H);          // NSETS*P
    int* rowstart = deg + (size_t)NSETS * P;                  // NSETS*RSP
    int* rank     = rowstart + (size_t)NSETS * RSP;           // NSETS*EDG
    int* elist    = rank + (size_t)NSETS * EDG;               // NSETS*EDG

    // ---- init X + zero deg/PL
    {
        int tot = NND * D + NSETS * P + NG * D;
        k_init_x<<<(tot + 255) / 256, 256, 0, stream>>>(x0, X, deg, PL);
    }
    // ---- weight prep
    {
        int tot = 4 * H * KP1 + 4 * H * H + 4 * D * H;
        k_wsplit_all<<<(tot + 255) / 256, 256, 0, stream>>>(W1, W2, W3, w1h, w1l, w2h, w2l, w3h, w3l);
    }
    // ---- CSR build
    k_csr_hist<<<(NSETS * EDG) / 256, 256, 0, stream>>>(inner_dst, fwd_dst, bwd_dst, deg, rank);
    k_csr_scan<<<NSETS, 1024, 0, stream>>>(deg, rowstart);
    k_csr_scatter<<<(NSETS * EDG) / 256, 256, 0, stream>>>(inner_src, inner_dst, fwd_src, fwd_dst,
                                                           bwd_src, bwd_dst, rowstart, rank, elist);

    auto mlp23 = [&](int set, int gbase_out) {
        k_mlp23<<<P / 64, 512, 0, stream>>>(
            H1h, H1l,
            w2h + (size_t)set * H * H, w2l + (size_t)set * H * H, b2 + set * H,
            w3h + (size_t)set * D * H, w3l + (size_t)set * D * H, b3 + set * D,
            X + (size_t)gbase_out * D);
    };
    auto conv = [&](int t, int dst_gbase, int src_gbase, int ei, int set) {
        k_gather_T<<<P / 4, 256, 0, stream>>>(
            X, stat, elist + (size_t)t * EDG, rowstart + (size_t)t * RSP,
            Th, Tl, dst_gbase, src_gbase, eps, ei);
        k_gemm_big<false><<<dim3(H / 128, P / 128), 512, 0, stream>>>(
            Th, Tl, KP1, nullptr, nullptr, 0,
            w1h + (size_t)set * H * KP1, w1l + (size_t)set * H * KP1, KP1,
            b1 + set * H, H1h, H1l, H);
        mlp23(set, dst_gbase);
    };
    auto node_dnn = [&](int gbase) {
        k_gemm_big<true><<<dim3(H / 128, P / 128), 512, 0, stream>>>(
            nullptr, nullptr, 0, X, stat, gbase,
            w1h + (size_t)3 * H * KP1, w1l + (size_t)3 * H * KP1, KP1,
            b1 + 3 * H, H1h, H1l, H);
        mlp23(3, gbase);
    };

    // forward pass
    for (int il = 0; il < NLAYERS; ++il) {
        int s0 = il * P;
        conv(il, s0, s0, 0, 0);                       // inner conv
        if (il == NLAYERS - 1) continue;
        conv(5 + il, s0 + P, s0, 1, 1);               // fwd conv
        node_dnn(s0 + P);
    }
    // backward pass
    for (int il = NLAYERS - 1; il >= 1; --il) {
        int s0 = (il - 1) * P;
        conv(9 + (il - 1), s0, s0 + P, 2, 2);         // bwd conv
        conv(il - 1, s0, s0, 0, 0);                   // inner conv
        node_dnn(s0);
    }

    k_pool2<<<NND / PROWS, 256, 0, stream>>>(X, bidx, PL);
    k_final<<<1, 64, 0, stream>>>(PL, lin_w, lin_b, (float*)d_out);
}